// Round 16
// baseline (33.056 us; speedup 1.0000x reference)
//
#include <hip/hip_runtime.h>

// PatchStd: out = sqrt( boxconv7(x^2) - boxconv7(x)^2 ), uniform 7x7 weight w.
// x: [16, 1, 1024, 1024] fp32, zero padding 3 on each side.
//
// R16 = R15's structure (wave-private LDS row-ring, global_load_lds DMA,
// counted s_waitcnt vmcnt, 4 cols/thread, in-loop stores) with the final
// amortization step + compensating depth:
//   SH=64  -> 256 blocks (1/CU), halo 1.1875 -> 1.094, warmups halved;
//   depth=6, RING=8 -> in-flight ~26 KB/CU, same as R15's (SH=64 at depth 3
//   would drop it to 13 KB and starve BW by Little's law).
// Wait table (R8/R11-validated formula, 2 loads/row + 1 store/output):
//   j<=6:12 | 7:13 | 8:14 | 9:15 | 10:16 | 11:17 | 12..63:18 |
//   64:16 | 65:14 | 66:12 | 67:10 | 68:8 | 69:6.   Never 0 mid-loop.
// SEGF=320 = full 64-lane DMA footprint (R9 lesson). No barriers.

#define IMG_W 1024
#define IMG_H 1024
#define SH    64            // output rows per block strip
#define TPB   256
#define NR    (SH + 6)      // 70 input rows per strip
#define RING  8
#define SEGF  320           // floats per LDS slot (272 used; 320 = DMA footprint)

typedef float v4f __attribute__((ext_vector_type(4)));

#define WAITV(N) asm volatile("s_waitcnt vmcnt(" #N ")" ::: "memory")

__global__ __launch_bounds__(TPB) void patchstd_kernel(
    const float* __restrict__ img, const float* __restrict__ wptr,
    float* __restrict__ out)
{
    __shared__ float lds[4 * RING * SEGF];          // 40 KB

    const int tx   = threadIdx.x;
    const int w_   = tx >> 6;                       // wave id 0..3 (uniform)
    const int lane = tx & 63;
    const int c0   = tx << 2;                       // first of 4 output cols
    const int y0   = blockIdx.y * SH;
    const float* base  = img + (size_t)blockIdx.z * (IMG_W * IMG_H);
    float*       obase = out + (size_t)blockIdx.z * (IMG_W * IMG_H);
    const float w = wptr[0];

    // Wave w_ covers output cols [256w, 256w+256); segment = cols Sw..Sw+271
    // (Sw = 256w-8); thread's 12-float window (c0-4..c0+7) is at segment
    // float index 4*lane+4. Per-lane global cols clamped in-row (clamped
    // lanes land in padding or are zero-patched at consume).
    const int Sw   = 256 * w_ - 8;
    const int colA = min(max(Sw + 4 * lane, 0), IMG_W - 4);   // dwordx4 quad
    const int colB = min(max(Sw + 256 + lane, 0), IMG_W - 1); // dword tail
    const float* gA = base + colA;
    const float* gB = base + colB;
    float* const seg0 = &lds[w_ * (RING * SEGF)];

    // Issue row j's segment DMA into ring slot j&7 (wave-uniform LDS base).
    auto issue = [&](int j) {
        const int rc = min(max(y0 - 3 + j, 0), IMG_H - 1);    // clamped row
        const size_t ro = (size_t)rc * IMG_W;
        float* sl = seg0 + (j & (RING - 1)) * SEGF;
        __builtin_amdgcn_global_load_lds(
            (const __attribute__((address_space(1))) void*)(gA + ro),
            (__attribute__((address_space(3))) void*)sl, 16, 0, 0);
        __builtin_amdgcn_global_load_lds(
            (const __attribute__((address_space(1))) void*)(gB + ro),
            (__attribute__((address_space(3))) void*)(sl + 256), 4, 0, 0);
    };

    // Horizontal 7-sums for 4 output cols from 12 raw values
    // (window for col c0+k = v[k+1..k+7]).
    auto hsum = [&](const float* v, float* h, float* q) {
        float s = v[1]+v[2]+v[3]+v[4]+v[5]+v[6]+v[7];
        h[0] = s;
        s = s - v[1] + v[8];  h[1] = s;
        s = s - v[2] + v[9];  h[2] = s;
        h[3] = s - v[3] + v[10];
        float sq[11];
        #pragma unroll
        for (int i = 1; i <= 10; ++i) sq[i] = v[i] * v[i];
        float t = sq[1]+sq[2]+sq[3]+sq[4]+sq[5]+sq[6]+sq[7];
        q[0] = t;
        t = t - sq[1] + sq[8];  q[1] = t;
        t = t - sq[2] + sq[9];  q[2] = t;
        q[3] = t - sq[3] + sq[10];
    };

    float rh[7][4], rq[7][4];                       // h/q ring (7 rows)
    float vh[4] = {0.f,0.f,0.f,0.f};                // vertical running sums
    float vq[4] = {0.f,0.f,0.f,0.f};

    // 6-deep pipeline fill: rows 0..5 in flight (12 vm-ops).
    issue(0); issue(1); issue(2); issue(3); issue(4); issue(5);

    // Full unroll: ring slots, vmcnt immediates, guards all compile-time.
    // Steady N = 2*depth + depth stores = 18 (derivation in header).
    #pragma unroll
    for (int j = 0; j < NR; ++j) {
        if (j + 6 < NR) issue(j + 6);

        if      (j <= 6)  WAITV(12);
        else if (j == 7)  WAITV(13);
        else if (j == 8)  WAITV(14);
        else if (j == 9)  WAITV(15);
        else if (j == 10) WAITV(16);
        else if (j == 11) WAITV(17);
        else if (j <= 63) WAITV(18);
        else if (j == 64) WAITV(16);
        else if (j == 65) WAITV(14);
        else if (j == 66) WAITV(12);
        else if (j == 67) WAITV(10);
        else if (j == 68) WAITV(8);
        else              WAITV(6);

        // Consume row j from LDS: 3x ds_read_b128.
        const float* seg = seg0 + (j & (RING - 1)) * SEGF;
        const v4f* p = (const v4f*)(seg + 4 * lane + 4);
        v4f A = p[0], B = p[1], C = p[2];
        float v[12] = {A.x,A.y,A.z,A.w, B.x,B.y,B.z,B.w, C.x,C.y,C.z,C.w};
        if (tx == 0)   { v[0]=0.f; v[1]=0.f; v[2]=0.f;  v[3]=0.f;  }
        if (tx == 255) { v[8]=0.f; v[9]=0.f; v[10]=0.f; v[11]=0.f; }

        float h[4], q[4];
        const int R = y0 - 3 + j;
        if (R < 0 || R >= IMG_H) {                  // block-uniform branch
            #pragma unroll
            for (int k = 0; k < 4; ++k) { h[k] = 0.f; q[k] = 0.f; }
        } else {
            hsum(v, h, q);
        }

        if (j < 6) {                                // warm the vertical window
            #pragma unroll
            for (int k = 0; k < 4; ++k) {
                rh[j][k] = h[k]; rq[j][k] = q[k];
                vh[k] += h[k];   vq[k] += q[k];
            }
            if (j == 5) {
                #pragma unroll
                for (int k = 0; k < 4; ++k) { rh[6][k] = 0.f; rq[6][k] = 0.f; }
            }
        } else {                                    // steady state: emit a row
            const int s = j % 7;                    // departing row's slot
            float o[4];
            #pragma unroll
            for (int k = 0; k < 4; ++k) {
                vh[k] += h[k] - rh[s][k];
                vq[k] += q[k] - rq[s][k];
                rh[s][k] = h[k]; rq[s][k] = q[k];
                float mean = w * vh[k];
                float var  = fmaf(w, vq[k], -(mean * mean));
                o[k] = __builtin_amdgcn_sqrtf(fmaxf(var, 0.f));
            }
            *reinterpret_cast<float4*>(obase + (size_t)(y0 + j - 6) * IMG_W + c0) =
                make_float4(o[0], o[1], o[2], o[3]);
        }
    }
}

extern "C" void kernel_launch(void* const* d_in, const int* in_sizes, int n_in,
                              void* d_out, int out_size, void* d_ws, size_t ws_size,
                              hipStream_t stream) {
    const float* img = (const float*)d_in[0];
    const float* wt  = (const float*)d_in[1];
    float* out = (float*)d_out;
    const int batch = in_sizes[0] / (IMG_W * IMG_H);   // 16
    dim3 grid(1, IMG_H / SH, batch);                   // (1, 16, 16) = 256 blocks
    patchstd_kernel<<<grid, dim3(TPB, 1, 1), 0, stream>>>(img, wt, out);
}

// Round 17
// 28.252 us; speedup vs baseline: 1.1700x; 1.1700x over previous
//
#include <hip/hip_runtime.h>

// PatchStd: out = sqrt( boxconv7(x^2) - boxconv7(x)^2 ), uniform 7x7 weight w.
// x: [16, 1, 1024, 1024] fp32, zero padding 3 on each side.
//
// R17 = R15 exactly (best, 28.06us: SH=32, 512 blocks = 2/CU, wave-private
// LDS row-ring, global_load_lds DMA, counted vmcnt, 4 cols/thread, in-loop
// stores) with ONE change: prefetch depth 3 -> 6 (RING=8, LDS 40KB).
// Isolated depth probe at the 8-waves/CU operating point: R10's depth-null
// was at SH=8 (16-32 waves/CU nominal); at R15's concurrency the in-flight
// bytes (~26KB/CU) are marginal by Little's law, and R16 confounded depth
// with 1-block/CU starvation. In-flight doubles to ~52KB/CU.
// Wait table (2 loads/row, 1 store/output, depth 6, NR=38):
//   j<=6:12 | 7:13 | 8:14 | 9:15 | 10:16 | 11:17 | 12..31:18 |
//   32:16 | 33:14 | 34:12 | 35:10 | 36:8 | 37:6.  Never 0 mid-loop.
// SEGF=320 = full 64-lane DMA footprint (R9 lesson). No barriers.

#define IMG_W 1024
#define IMG_H 1024
#define SH    32            // output rows per block strip
#define TPB   256
#define NR    (SH + 6)      // 38 input rows per strip
#define RING  8
#define SEGF  320           // floats per LDS slot (272 used; 320 = DMA footprint)

typedef float v4f __attribute__((ext_vector_type(4)));

#define WAITV(N) asm volatile("s_waitcnt vmcnt(" #N ")" ::: "memory")

__global__ __launch_bounds__(TPB) void patchstd_kernel(
    const float* __restrict__ img, const float* __restrict__ wptr,
    float* __restrict__ out)
{
    __shared__ float lds[4 * RING * SEGF];          // 40 KB

    const int tx   = threadIdx.x;
    const int w_   = tx >> 6;                       // wave id 0..3 (uniform)
    const int lane = tx & 63;
    const int c0   = tx << 2;                       // first of 4 output cols
    const int y0   = blockIdx.y * SH;
    const float* base  = img + (size_t)blockIdx.z * (IMG_W * IMG_H);
    float*       obase = out + (size_t)blockIdx.z * (IMG_W * IMG_H);
    const float w = wptr[0];

    // Wave w_ covers output cols [256w, 256w+256); segment = cols Sw..Sw+271
    // (Sw = 256w-8); thread's 12-float window (c0-4..c0+7) is at segment
    // float index 4*lane+4. Per-lane global cols clamped in-row (clamped
    // lanes land in padding or are zero-patched at consume).
    const int Sw   = 256 * w_ - 8;
    const int colA = min(max(Sw + 4 * lane, 0), IMG_W - 4);   // dwordx4 quad
    const int colB = min(max(Sw + 256 + lane, 0), IMG_W - 1); // dword tail
    const float* gA = base + colA;
    const float* gB = base + colB;
    float* const seg0 = &lds[w_ * (RING * SEGF)];

    // Issue row j's segment DMA into ring slot j&7 (wave-uniform LDS base).
    auto issue = [&](int j) {
        const int rc = min(max(y0 - 3 + j, 0), IMG_H - 1);    // clamped row
        const size_t ro = (size_t)rc * IMG_W;
        float* sl = seg0 + (j & (RING - 1)) * SEGF;
        __builtin_amdgcn_global_load_lds(
            (const __attribute__((address_space(1))) void*)(gA + ro),
            (__attribute__((address_space(3))) void*)sl, 16, 0, 0);
        __builtin_amdgcn_global_load_lds(
            (const __attribute__((address_space(1))) void*)(gB + ro),
            (__attribute__((address_space(3))) void*)(sl + 256), 4, 0, 0);
    };

    // Horizontal 7-sums for 4 output cols from 12 raw values
    // (window for col c0+k = v[k+1..k+7]).
    auto hsum = [&](const float* v, float* h, float* q) {
        float s = v[1]+v[2]+v[3]+v[4]+v[5]+v[6]+v[7];
        h[0] = s;
        s = s - v[1] + v[8];  h[1] = s;
        s = s - v[2] + v[9];  h[2] = s;
        h[3] = s - v[3] + v[10];
        float sq[11];
        #pragma unroll
        for (int i = 1; i <= 10; ++i) sq[i] = v[i] * v[i];
        float t = sq[1]+sq[2]+sq[3]+sq[4]+sq[5]+sq[6]+sq[7];
        q[0] = t;
        t = t - sq[1] + sq[8];  q[1] = t;
        t = t - sq[2] + sq[9];  q[2] = t;
        q[3] = t - sq[3] + sq[10];
    };

    float rh[7][4], rq[7][4];                       // h/q ring (7 rows)
    float vh[4] = {0.f,0.f,0.f,0.f};                // vertical running sums
    float vq[4] = {0.f,0.f,0.f,0.f};

    // 6-deep pipeline fill: rows 0..5 in flight (12 vm-ops).
    issue(0); issue(1); issue(2); issue(3); issue(4); issue(5);

    // Full unroll: ring slots, vmcnt immediates, guards all compile-time.
    #pragma unroll
    for (int j = 0; j < NR; ++j) {
        if (j + 6 < NR) issue(j + 6);

        if      (j <= 6)  WAITV(12);
        else if (j == 7)  WAITV(13);
        else if (j == 8)  WAITV(14);
        else if (j == 9)  WAITV(15);
        else if (j == 10) WAITV(16);
        else if (j == 11) WAITV(17);
        else if (j <= 31) WAITV(18);
        else if (j == 32) WAITV(16);
        else if (j == 33) WAITV(14);
        else if (j == 34) WAITV(12);
        else if (j == 35) WAITV(10);
        else if (j == 36) WAITV(8);
        else              WAITV(6);

        // Consume row j from LDS: 3x ds_read_b128.
        const float* seg = seg0 + (j & (RING - 1)) * SEGF;
        const v4f* p = (const v4f*)(seg + 4 * lane + 4);
        v4f A = p[0], B = p[1], C = p[2];
        float v[12] = {A.x,A.y,A.z,A.w, B.x,B.y,B.z,B.w, C.x,C.y,C.z,C.w};
        if (tx == 0)   { v[0]=0.f; v[1]=0.f; v[2]=0.f;  v[3]=0.f;  }
        if (tx == 255) { v[8]=0.f; v[9]=0.f; v[10]=0.f; v[11]=0.f; }

        float h[4], q[4];
        const int R = y0 - 3 + j;
        if (R < 0 || R >= IMG_H) {                  // block-uniform branch
            #pragma unroll
            for (int k = 0; k < 4; ++k) { h[k] = 0.f; q[k] = 0.f; }
        } else {
            hsum(v, h, q);
        }

        if (j < 6) {                                // warm the vertical window
            #pragma unroll
            for (int k = 0; k < 4; ++k) {
                rh[j][k] = h[k]; rq[j][k] = q[k];
                vh[k] += h[k];   vq[k] += q[k];
            }
            if (j == 5) {
                #pragma unroll
                for (int k = 0; k < 4; ++k) { rh[6][k] = 0.f; rq[6][k] = 0.f; }
            }
        } else {                                    // steady state: emit a row
            const int s = j % 7;                    // departing row's slot
            float o[4];
            #pragma unroll
            for (int k = 0; k < 4; ++k) {
                vh[k] += h[k] - rh[s][k];
                vq[k] += q[k] - rq[s][k];
                rh[s][k] = h[k]; rq[s][k] = q[k];
                float mean = w * vh[k];
                float var  = fmaf(w, vq[k], -(mean * mean));
                o[k] = __builtin_amdgcn_sqrtf(fmaxf(var, 0.f));
            }
            *reinterpret_cast<float4*>(obase + (size_t)(y0 + j - 6) * IMG_W + c0) =
                make_float4(o[0], o[1], o[2], o[3]);
        }
    }
}

extern "C" void kernel_launch(void* const* d_in, const int* in_sizes, int n_in,
                              void* d_out, int out_size, void* d_ws, size_t ws_size,
                              hipStream_t stream) {
    const float* img = (const float*)d_in[0];
    const float* wt  = (const float*)d_in[1];
    float* out = (float*)d_out;
    const int batch = in_sizes[0] / (IMG_W * IMG_H);   // 16
    dim3 grid(1, IMG_H / SH, batch);                   // 512 blocks = 2/CU
    patchstd_kernel<<<grid, dim3(TPB, 1, 1), 0, stream>>>(img, wt, out);
}

// Round 18
// 27.253 us; speedup vs baseline: 1.2129x; 1.0367x over previous
//
#include <hip/hip_runtime.h>

// PatchStd: out = sqrt( boxconv7(x^2) - boxconv7(x)^2 ), uniform 7x7 weight w.
// x: [16, 1, 1024, 1024] fp32, zero padding 3 on each side.
//
// R18 = R15 exactly (best, 28.06us: SH=32, 512 blocks = 2/CU, wave-private
// LDS row-ring, RING=4, global_load_lds DMA 3 ahead, counted vmcnt,
// 4 cols/thread, in-loop stores) + two MEMORY-SYSTEM-only changes (every
// wave-schedule lever is proven null, R10/R12/R13/R14/R16/R17):
//  1) nontemporal output stores — 64MB streaming writes no longer allocate
//     in the 4MiB/XCD L2, preserving input-row residency and cutting TCC
//     write contention against the DMA fills;
//  2) XCD-pair swizzle — flat-grid decode places strips (y,y+1) of the same
//     image 256 block-ids apart (same XCD under id%8 round-robin), so the 6
//     shared halo rows are L2-hits instead of HBM re-fetches. Locality-only
//     (correct under any mapping, G16-safe).
// SEGF=320 = full 64-lane DMA footprint (R9 lesson). No barriers.

#define IMG_W 1024
#define IMG_H 1024
#define SH    32            // output rows per block strip
#define TPB   256
#define NR    (SH + 6)      // 38 input rows per strip
#define RING  4
#define SEGF  320           // floats per LDS slot (272 used; 320 = DMA footprint)

typedef float v4f __attribute__((ext_vector_type(4)));

#define WAITV(N) asm volatile("s_waitcnt vmcnt(" #N ")" ::: "memory")

__global__ __launch_bounds__(TPB) void patchstd_kernel(
    const float* __restrict__ img, const float* __restrict__ wptr,
    float* __restrict__ out)
{
    __shared__ float lds[4 * RING * SEGF];          // 20 KB

    const int tx   = threadIdx.x;
    const int w_   = tx >> 6;                       // wave id 0..3 (uniform)
    const int lane = tx & 63;
    const int c0   = tx << 2;                       // first of 4 output cols

    // XCD-pair swizzle: bid = b*256 + p*16 + z with y = 2p + b.
    // y and y+1 (same z) differ by 256 in bid -> same residue mod 8.
    const int bid = blockIdx.x;
    const int b   = bid >> 8;                       // 0..1
    const int p   = (bid >> 4) & 15;                // 0..15
    const int z   = bid & 15;                       // image index 0..15
    const int y0  = (2 * p + b) * SH;

    const float* base  = img + (size_t)z * (IMG_W * IMG_H);
    float*       obase = out + (size_t)z * (IMG_W * IMG_H);
    const float w = wptr[0];

    // Wave w_ covers output cols [256w, 256w+256); segment = cols Sw..Sw+271
    // (Sw = 256w-8); thread's 12-float window (c0-4..c0+7) is at segment
    // float index 4*lane+4. Per-lane global cols clamped in-row (clamped
    // lanes land in padding or are zero-patched at consume).
    const int Sw   = 256 * w_ - 8;
    const int colA = min(max(Sw + 4 * lane, 0), IMG_W - 4);   // dwordx4 quad
    const int colB = min(max(Sw + 256 + lane, 0), IMG_W - 1); // dword tail
    const float* gA = base + colA;
    const float* gB = base + colB;
    float* const seg0 = &lds[w_ * (RING * SEGF)];

    // Issue row j's segment DMA into ring slot j&3 (wave-uniform LDS base).
    auto issue = [&](int j) {
        const int rc = min(max(y0 - 3 + j, 0), IMG_H - 1);    // clamped row
        const size_t ro = (size_t)rc * IMG_W;
        float* sl = seg0 + (j & (RING - 1)) * SEGF;
        __builtin_amdgcn_global_load_lds(
            (const __attribute__((address_space(1))) void*)(gA + ro),
            (__attribute__((address_space(3))) void*)sl, 16, 0, 0);
        __builtin_amdgcn_global_load_lds(
            (const __attribute__((address_space(1))) void*)(gB + ro),
            (__attribute__((address_space(3))) void*)(sl + 256), 4, 0, 0);
    };

    // Horizontal 7-sums for 4 output cols from 12 raw values
    // (window for col c0+k = v[k+1..k+7]).
    auto hsum = [&](const float* v, float* h, float* q) {
        float s = v[1]+v[2]+v[3]+v[4]+v[5]+v[6]+v[7];
        h[0] = s;
        s = s - v[1] + v[8];  h[1] = s;
        s = s - v[2] + v[9];  h[2] = s;
        h[3] = s - v[3] + v[10];
        float sq[11];
        #pragma unroll
        for (int i = 1; i <= 10; ++i) sq[i] = v[i] * v[i];
        float t = sq[1]+sq[2]+sq[3]+sq[4]+sq[5]+sq[6]+sq[7];
        q[0] = t;
        t = t - sq[1] + sq[8];  q[1] = t;
        t = t - sq[2] + sq[9];  q[2] = t;
        q[3] = t - sq[3] + sq[10];
    };

    float rh[7][4], rq[7][4];                       // h/q ring (7 rows)
    float vh[4] = {0.f,0.f,0.f,0.f};                // vertical running sums
    float vq[4] = {0.f,0.f,0.f,0.f};

    issue(0); issue(1); issue(2);                   // 3-deep pipeline fill

    // Full unroll: ring slots, vmcnt immediates, guards all compile-time.
    // vmcnt table = R15's validated set (2 loads/row, 1 store/output):
    //   j<=6:6 | 7:7 | 8:8 | 9..34:9 | 35:7 | 36:5 | 37:3.
    #pragma unroll
    for (int j = 0; j < NR; ++j) {
        if (j + 3 < NR) issue(j + 3);

        if      (j <= 6)  WAITV(6);
        else if (j == 7)  WAITV(7);
        else if (j == 8)  WAITV(8);
        else if (j <= 34) WAITV(9);
        else if (j == 35) WAITV(7);
        else if (j == 36) WAITV(5);
        else              WAITV(3);

        // Consume row j from LDS: 3x ds_read_b128.
        const float* seg = seg0 + (j & (RING - 1)) * SEGF;
        const v4f* pq = (const v4f*)(seg + 4 * lane + 4);
        v4f A = pq[0], B = pq[1], C = pq[2];
        float v[12] = {A.x,A.y,A.z,A.w, B.x,B.y,B.z,B.w, C.x,C.y,C.z,C.w};
        if (tx == 0)   { v[0]=0.f; v[1]=0.f; v[2]=0.f;  v[3]=0.f;  }
        if (tx == 255) { v[8]=0.f; v[9]=0.f; v[10]=0.f; v[11]=0.f; }

        float h[4], q[4];
        const int R = y0 - 3 + j;
        if (R < 0 || R >= IMG_H) {                  // block-uniform branch
            #pragma unroll
            for (int k = 0; k < 4; ++k) { h[k] = 0.f; q[k] = 0.f; }
        } else {
            hsum(v, h, q);
        }

        if (j < 6) {                                // warm the vertical window
            #pragma unroll
            for (int k = 0; k < 4; ++k) {
                rh[j][k] = h[k]; rq[j][k] = q[k];
                vh[k] += h[k];   vq[k] += q[k];
            }
            if (j == 5) {
                #pragma unroll
                for (int k = 0; k < 4; ++k) { rh[6][k] = 0.f; rq[6][k] = 0.f; }
            }
        } else {                                    // steady state: emit a row
            const int s = j % 7;                    // departing row's slot
            float o[4];
            #pragma unroll
            for (int k = 0; k < 4; ++k) {
                vh[k] += h[k] - rh[s][k];
                vq[k] += q[k] - rq[s][k];
                rh[s][k] = h[k]; rq[s][k] = q[k];
                float mean = w * vh[k];
                float var  = fmaf(w, vq[k], -(mean * mean));
                o[k] = __builtin_amdgcn_sqrtf(fmaxf(var, 0.f));
            }
            v4f ov; ov.x = o[0]; ov.y = o[1]; ov.z = o[2]; ov.w = o[3];
            __builtin_nontemporal_store(
                ov, reinterpret_cast<v4f*>(obase + (size_t)(y0 + j - 6) * IMG_W + c0));
        }
    }
}

extern "C" void kernel_launch(void* const* d_in, const int* in_sizes, int n_in,
                              void* d_out, int out_size, void* d_ws, size_t ws_size,
                              hipStream_t stream) {
    const float* img = (const float*)d_in[0];
    const float* wt  = (const float*)d_in[1];
    float* out = (float*)d_out;
    (void)in_sizes; (void)n_in; (void)d_ws; (void)ws_size; (void)out_size;
    dim3 grid(512, 1, 1);                              // flat; decoded in-kernel
    patchstd_kernel<<<grid, dim3(TPB, 1, 1), 0, stream>>>(img, wt, out);
}

// Round 19
// 26.368 us; speedup vs baseline: 1.2537x; 1.0336x over previous
//
#include <hip/hip_runtime.h>

// PatchStd: out = sqrt( boxconv7(x^2) - boxconv7(x)^2 ), uniform 7x7 weight w.
// x: [16, 1, 1024, 1024] fp32, zero padding 3 on each side.
//
// R19 = R18 (27.25us: SH=32, 512 blocks=2/CU, LDS row-ring RING=4, DMA 3
// ahead, counted vmcnt, NT stores, XCD-pair swizzle) with the staging made
// BLOCK-COOPERATIVE: the 4 waves' size-16 DMAs tile the full 1024-col row
// exactly (src col = 4*tx, no clamp, NO tail op) — 4 DMA ops / 4.1KB per
// block-row instead of 8 ops / 5.1KB. Halo (+-4 cols) is read from neighbor
// waves' segments in LDS, synchronized by raw s_barrier preceded by each
// wave's counted WAITV (no full-drain __syncthreads). issue(j+3) placed
// AFTER the barrier: it overwrites slot (j-1)&3, whose readers all passed
// this barrier; consumed slot j differs from written slot (j+3)&3.
// Slot = 1032 floats: 4-float guard front/back so edge threads' b128 reads
// stay in-bounds (guards zero-patched in regs).
// Wait table (1 load/row + 1 store/output; issue after barrier, wait before):
//   j<=6:2 | 7:3 | 8:4 | 9..35:5 | 36:4 | 37:3.  Never 0 mid-loop.

#define IMG_W 1024
#define IMG_H 1024
#define SH    32            // output rows per block strip
#define TPB   256
#define NR    (SH + 6)      // 38 input rows per strip
#define RING  4
#define SLOTF 1032          // 4 guard + 1024 data + 4 guard (floats)

typedef float v4f __attribute__((ext_vector_type(4)));

#define WAITV(N) asm volatile("s_waitcnt vmcnt(" #N ")" ::: "memory")

__global__ __launch_bounds__(TPB) void patchstd_kernel(
    const float* __restrict__ img, const float* __restrict__ wptr,
    float* __restrict__ out)
{
    __shared__ float lds[RING * SLOTF];             // 16.5 KB

    const int tx   = threadIdx.x;
    const int w_   = tx >> 6;                       // wave id 0..3 (uniform)
    const int c0   = tx << 2;                       // first of 4 output cols

    // XCD-pair swizzle (R18): bid = b*256 + p*16 + z with y = 2p + b.
    const int bid = blockIdx.x;
    const int b   = bid >> 8;                       // 0..1
    const int p   = (bid >> 4) & 15;                // 0..15
    const int z   = bid & 15;                       // image index 0..15
    const int y0  = (2 * p + b) * SH;

    const float* base  = img + (size_t)z * (IMG_W * IMG_H);
    float*       obase = out + (size_t)z * (IMG_W * IMG_H);
    const float w = wptr[0];

    // Block-cooperative staging: lane src col = 4*tx (exact row tiling, no
    // clamp); wave w_ writes slot floats [4+256w .. 4+256w+255].
    const float* gP = base + c0;

    auto issue = [&](int j) {
        const int rc = min(max(y0 - 3 + j, 0), IMG_H - 1);    // clamped row
        __builtin_amdgcn_global_load_lds(
            (const __attribute__((address_space(1))) void*)(gP + (size_t)rc * IMG_W),
            (__attribute__((address_space(3))) void*)
                (&lds[(j & (RING - 1)) * SLOTF + 4 + 256 * w_]), 16, 0, 0);
    };

    // Horizontal 7-sums for 4 output cols from 12 raw values
    // (window for col c0+k = v[k+1..k+7]).
    auto hsum = [&](const float* v, float* h, float* q) {
        float s = v[1]+v[2]+v[3]+v[4]+v[5]+v[6]+v[7];
        h[0] = s;
        s = s - v[1] + v[8];  h[1] = s;
        s = s - v[2] + v[9];  h[2] = s;
        h[3] = s - v[3] + v[10];
        float sq[11];
        #pragma unroll
        for (int i = 1; i <= 10; ++i) sq[i] = v[i] * v[i];
        float t = sq[1]+sq[2]+sq[3]+sq[4]+sq[5]+sq[6]+sq[7];
        q[0] = t;
        t = t - sq[1] + sq[8];  q[1] = t;
        t = t - sq[2] + sq[9];  q[2] = t;
        q[3] = t - sq[3] + sq[10];
    };

    float rh[7][4], rq[7][4];                       // h/q ring (7 rows)
    float vh[4] = {0.f,0.f,0.f,0.f};                // vertical running sums
    float vq[4] = {0.f,0.f,0.f,0.f};

    issue(0); issue(1); issue(2);                   // 3-deep pipeline fill

    // Full unroll: slots, vmcnt immediates, guards all compile-time.
    #pragma unroll
    for (int j = 0; j < NR; ++j) {
        // Own row-j DMA complete -> barrier -> all segments of row j visible.
        if      (j <= 6)  WAITV(2);
        else if (j == 7)  WAITV(3);
        else if (j == 8)  WAITV(4);
        else if (j <= 35) WAITV(5);
        else if (j == 36) WAITV(4);
        else              WAITV(3);
        __builtin_amdgcn_s_barrier();
        asm volatile("" ::: "memory");              // no compiler reordering

        if (j + 3 < NR) issue(j + 3);               // overwrites slot (j-1)&3:
                                                    // its readers passed this barrier

        // Consume row j: window cols c0-4..c0+7 = slot floats c0..c0+11
        // (data col c at slot float 4+c; tx edge quads hit guards -> patched).
        const float* seg = &lds[(j & (RING - 1)) * SLOTF + c0];
        const v4f* pq = (const v4f*)seg;
        v4f A = pq[0], B = pq[1], C = pq[2];
        float v[12] = {A.x,A.y,A.z,A.w, B.x,B.y,B.z,B.w, C.x,C.y,C.z,C.w};
        if (tx == 0)   { v[0]=0.f; v[1]=0.f; v[2]=0.f;  v[3]=0.f;  }
        if (tx == 255) { v[8]=0.f; v[9]=0.f; v[10]=0.f; v[11]=0.f; }

        float h[4], q[4];
        const int R = y0 - 3 + j;
        if (R < 0 || R >= IMG_H) {                  // block-uniform branch
            #pragma unroll
            for (int k = 0; k < 4; ++k) { h[k] = 0.f; q[k] = 0.f; }
        } else {
            hsum(v, h, q);
        }

        if (j < 6) {                                // warm the vertical window
            #pragma unroll
            for (int k = 0; k < 4; ++k) {
                rh[j][k] = h[k]; rq[j][k] = q[k];
                vh[k] += h[k];   vq[k] += q[k];
            }
            if (j == 5) {
                #pragma unroll
                for (int k = 0; k < 4; ++k) { rh[6][k] = 0.f; rq[6][k] = 0.f; }
            }
        } else {                                    // steady state: emit a row
            const int s = j % 7;                    // departing row's slot
            float o[4];
            #pragma unroll
            for (int k = 0; k < 4; ++k) {
                vh[k] += h[k] - rh[s][k];
                vq[k] += q[k] - rq[s][k];
                rh[s][k] = h[k]; rq[s][k] = q[k];
                float mean = w * vh[k];
                float var  = fmaf(w, vq[k], -(mean * mean));
                o[k] = __builtin_amdgcn_sqrtf(fmaxf(var, 0.f));
            }
            v4f ov; ov.x = o[0]; ov.y = o[1]; ov.z = o[2]; ov.w = o[3];
            __builtin_nontemporal_store(
                ov, reinterpret_cast<v4f*>(obase + (size_t)(y0 + j - 6) * IMG_W + c0));
        }
    }
}

extern "C" void kernel_launch(void* const* d_in, const int* in_sizes, int n_in,
                              void* d_out, int out_size, void* d_ws, size_t ws_size,
                              hipStream_t stream) {
    const float* img = (const float*)d_in[0];
    const float* wt  = (const float*)d_in[1];
    float* out = (float*)d_out;
    (void)in_sizes; (void)n_in; (void)d_ws; (void)ws_size; (void)out_size;
    dim3 grid(512, 1, 1);                              // flat; decoded in-kernel
    patchstd_kernel<<<grid, dim3(TPB, 1, 1), 0, stream>>>(img, wt, out);
}